// Round 9
// baseline (366.693 us; speedup 1.0000x reference)
//
#include <hip/hip_runtime.h>
#include <hip/hip_bf16.h>
#include <math.h>

// ---------------------------------------------------------------------------
// RPN fused kernel for MI355X (gfx950)
//   trunk : 3x3 conv 64->512 + bias + relu   (fp16 single-pass MFMA)
//   heads : 1x1 conv 512->9 (sigmoid) and 512->36 (linear), deltas masked by
//           score > 0.7, output [B,H,W,45] fp32
// Round 8b: identical to Round 8 (L2-residency fix: nontemporal x loads +
//   out stores so btI stays L2-resident; read-coalesced prep) with the
//   compile fix: __builtin_nontemporal_load needs a clang ext_vector_type
//   pointee, not HIP's float4 struct -> f32x4 typedef used for the load.
// ---------------------------------------------------------------------------

typedef _Float16 fp16x8 __attribute__((ext_vector_type(8)));
typedef _Float16 fp16x4 __attribute__((ext_vector_type(4)));
typedef float    f32x4  __attribute__((ext_vector_type(4)));

#define BT_ELEMS  (18 * 32 * 64 * 8)    // 294912 trunk weights fp16
#define BT2_ELEMS (48 * 512)            // head weights, [o][k] k-major

__device__ __forceinline__ void gl_lds16(const void* g, void* l) {
    __builtin_amdgcn_global_load_lds(
        (const __attribute__((address_space(1))) void*)g,
        (__attribute__((address_space(3))) void*)l, 16, 0, 0);
}

// ---------------------------------------------------------------------------
// prep: trunk weights -> fp16 bt[s][j=wv*8+l][lane][8]  (exact LDS staging
//       order); head weights -> fp16 hi/lo [o][k]
//   Read-coalesced: thread t <-> wb flat element t = kg*512 + n.
// ---------------------------------------------------------------------------
__global__ __launch_bounds__(256) void rpn_prep(
    const float* __restrict__ wb,   // [3][3][64][512]  flat: [kg][n]
    const float* __restrict__ wc,   // [512][9]
    const float* __restrict__ wr,   // [512][36]
    _Float16* __restrict__ btI,
    _Float16* __restrict__ bt2_hi, _Float16* __restrict__ bt2_lo)
{
    int t = blockIdx.x * 256 + threadIdx.x;
    if (t < BT_ELEMS) {
        int n  = t & 511;
        int kg = t >> 9;                 // 0..575
        float v = __builtin_nontemporal_load(wb + t);
        int s  = kg >> 5;                // k-chunk 0..17
        int kk = kg & 31;
        int q  = kk >> 3, e = kk & 7;
        int wv = n >> 7, l = (n >> 4) & 7, lr = n & 15;
        int lane = q * 16 + lr;
        btI[(((s * 32 + wv * 8 + l) * 64) + lane) * 8 + e] = (_Float16)v;
    } else if (t < BT_ELEMS + BT2_ELEMS) {
        int jj = t - BT_ELEMS;
        int k = jj & 511;
        int o = jj >> 9;                 // 0..47
        float v = 0.f;
        if (o < 9)       v = wc[k * 9 + o];
        else if (o < 45) v = wr[k * 36 + (o - 9)];
        _Float16 h = (_Float16)v;
        bt2_hi[jj] = h;
        bt2_lo[jj] = (_Float16)(v - (float)h);
    }
}

// ---------------------------------------------------------------------------
// main fused kernel: 4096 workgroups x 256 threads
//   tile = 64 output positions (2 h-rows x 32 w) x 512 channels
//   wave w owns channel slice [128w, 128w+128); acc[4][8] = 128 AGPR
// LDS arena (52352 B):
//   [0, 32768)        B-slots: wave w owns [w*8192, w*8192+8192)
//   [32768, +19584)   xs_hi [4][34][72] fp16
//   head phase reuses [0, 49152): zbuf float[64][48] @0,
//   fbuf per wave @12288 + w*9216 (fh [64][36] fp16, fl +4608 B)
// ---------------------------------------------------------------------------
#define BS_BYTES    32768
#define XS_HI_OFF   32768
#define FB_OFF      12288
#define FB_PER_WAVE 9216
#define ARENA_BYTES 52352

__global__ __launch_bounds__(256, 2) void rpn_main(
    const float* __restrict__ x,        // [4][256][256][64]
    const float* __restrict__ b_base,   // [512]
    const float* __restrict__ b_cls,    // [9]
    const float* __restrict__ b_reg,    // [36]
    const _Float16* __restrict__ btI,
    const _Float16* __restrict__ bt2_hi, const _Float16* __restrict__ bt2_lo,
    float* __restrict__ out)            // [4][256][256][45]
{
    __shared__ char smem[ARENA_BYTES];
    _Float16* xs_hi = (_Float16*)(smem + XS_HI_OFF);
    float*    zbuf  = (float*)smem;

    const int tid  = threadIdx.x;
    const int wave = tid >> 6;
    const int lane = tid & 63;
    const int q    = lane >> 4;     // 0..3
    const int lr   = lane & 15;     // 0..15
    const int n0   = wave * 128;    // wave's channel-slice base

    const int wg  = blockIdx.x;
    const int b   = wg >> 10;           // 1024 tiles per image
    const int rem = wg & 1023;
    const int h0  = (rem >> 3) * 2;     // 2 h-rows per tile
    const int w0  = (rem & 7) * 32;     // 32 w-positions per tile

    // wave-private B staging pointers
    char* bsw = smem + wave * 8192;                       // LDS slot
    const char* gB0 = (const char*)btI + wave * 8192 + lane * 16;

    // ---- issue B stage for s=0 (latency overlaps x staging) ----
    #pragma unroll
    for (int i = 0; i < 8; ++i)
        gl_lds16(gB0 + i * 1024, bsw + i * 1024);

    // ---- stage x patch (4 rows x 34 pos x 64 ch) as fp16, nontemporal ----
    for (int i = 0; i < 9; ++i) {
        int flat = tid + i * 256;
        if (flat < 4 * 34 * 16) {
            int cq  = flat & 15;          // channel quad
            int rp  = flat >> 4;          // 0..135
            int row = rp / 34;
            int pos = rp - row * 34;
            int hh  = h0 - 1 + row;
            int ww  = w0 - 1 + pos;
            fp16x4 h4;
            if (hh >= 0 && hh < 256 && ww >= 0 && ww < 256) {
                const f32x4* gp = (const f32x4*)&x[(((b * 256 + hh) * 256 + ww) * 64 + cq * 4)];
                const f32x4 v = __builtin_nontemporal_load(gp);
                h4[0] = (_Float16)v.x; h4[1] = (_Float16)v.y;
                h4[2] = (_Float16)v.z; h4[3] = (_Float16)v.w;
            } else {
                #pragma unroll
                for (int j = 0; j < 4; ++j) h4[j] = (_Float16)0.f;
            }
            *(fp16x4*)&xs_hi[(row * 34 + pos) * 72 + cq * 4] = h4;
        }
    }
    asm volatile("s_waitcnt vmcnt(0)" ::: "memory");  // B0 landed
    __syncthreads();   // barrier 1: xs + B0 ready

    // ---- trunk K-loop: 18 s-steps, barrier-free, LDS-DMA weight pipeline ----
    f32x4 acc[4][8];
    #pragma unroll
    for (int km = 0; km < 4; ++km)
        #pragma unroll
        for (int l = 0; l < 8; ++l)
            acc[km][l] = (f32x4){0.f, 0.f, 0.f, 0.f};

    const _Float16* bsr = (const _Float16*)(bsw + lane * 16);  // frag base

    for (int s = 0; s < 18; ++s) {
        const int tap = s >> 1;
        const int ky  = tap / 3;
        const int kx  = tap - ky * 3;
        const int c0  = (s & 1) * 32 + q * 8;
        // A-frags from xs (disjoint from B slots -> safe before vmcnt wait)
        fp16x8 ah[4];
        #pragma unroll
        for (int km = 0; km < 4; ++km) {
            int rowp = (km >> 1) + ky;
            int pos  = ((km & 1) << 4) + lr + kx;
            ah[km] = *(const fp16x8*)&xs_hi[(rowp * 34 + pos) * 72 + c0];
        }
        asm volatile("s_waitcnt vmcnt(0)" ::: "memory");  // B(s) landed
        // B-frags LDS -> VGPR (frees the slot for the next DMA)
        fp16x8 bh[8];
        #pragma unroll
        for (int l = 0; l < 8; ++l)
            bh[l] = *(const fp16x8*)(bsr + l * 512);       // l*1024 bytes
        asm volatile("s_waitcnt lgkmcnt(0)" ::: "memory"); // frag reads retired
        if (s < 17) {
            // slot free: issue DMA for s+1 NOW; it overlaps the MFMA block
            const char* gBs = gB0 + (size_t)(s + 1) * BS_BYTES;
            #pragma unroll
            for (int i = 0; i < 8; ++i)
                gl_lds16(gBs + i * 1024, bsw + i * 1024);
        }
        // 32 MFMAs from registers (single-pass: x_h * w_h)
        #pragma unroll
        for (int l = 0; l < 8; ++l) {
            acc[0][l] = __builtin_amdgcn_mfma_f32_16x16x32_f16(ah[0], bh[l], acc[0][l], 0, 0, 0);
            acc[1][l] = __builtin_amdgcn_mfma_f32_16x16x32_f16(ah[1], bh[l], acc[1][l], 0, 0, 0);
            acc[2][l] = __builtin_amdgcn_mfma_f32_16x16x32_f16(ah[2], bh[l], acc[2][l], 0, 0, 0);
            acc[3][l] = __builtin_amdgcn_mfma_f32_16x16x32_f16(ah[3], bh[l], acc[3][l], 0, 0, 0);
        }
    }

    __syncthreads();   // barrier 2: trunk done (all DMAs drained), arena reusable

    // ---- fused 1x1 heads: per-wave k-slice GEMM feat[64][128] x w2[128][48] ----
    _Float16* fh = (_Float16*)(smem + FB_OFF + wave * FB_PER_WAVE);
    _Float16* fl = fh + 64 * 36;

    f32x4 acc2[4][3];
    #pragma unroll
    for (int km = 0; km < 4; ++km)
        #pragma unroll
        for (int ns = 0; ns < 3; ++ns)
            acc2[km][ns] = (f32x4){0.f, 0.f, 0.f, 0.f};

    for (int sub = 0; sub < 4; ++sub) {       // 4 k-chunks of 32 within the slice
        // dump this wave's 32-channel slice of feat (bias+relu, fp16 hi/lo)
        #pragma unroll
        for (int lh = 0; lh < 2; ++lh) {
            int l = sub * 2 + lh;
            float bias = b_base[n0 + l * 16 + lr];
            #pragma unroll
            for (int km = 0; km < 4; ++km) {
                #pragma unroll
                for (int r = 0; r < 4; ++r) {
                    float v = acc[km][l][r] + bias;
                    v = v > 0.f ? v : 0.f;
                    _Float16 h = (_Float16)v;
                    int row = km * 16 + q * 4 + r;
                    int col = lh * 16 + lr;
                    fh[row * 36 + col] = h;
                    fl[row * 36 + col] = (_Float16)(v - (float)h);
                }
            }
        }
        asm volatile("s_waitcnt lgkmcnt(0)" ::: "memory");  // wave-local RAW fence

        // A-frags: feat rows, k-local = q*8..q*8+7 (8-byte aligned -> 2x b64)
        fp16x8 fah[4], fal[4];
        #pragma unroll
        for (int km = 0; km < 4; ++km) {
            int off = (km * 16 + lr) * 36 + q * 8;
            union { fp16x8 v8; fp16x4 v4[2]; } uh, ul;
            uh.v4[0] = *(const fp16x4*)&fh[off];
            uh.v4[1] = *(const fp16x4*)&fh[off + 4];
            ul.v4[0] = *(const fp16x4*)&fl[off];
            ul.v4[1] = *(const fp16x4*)&fl[off + 4];
            fah[km] = uh.v8;
            fal[km] = ul.v8;
        }

        const int kg = n0 + sub * 32 + q * 8;   // global k for B frags
        // ns = 0 (contains the 9 score cols): 3-pass hi/lo
        {
            int eo = (0 * 16 + lr) * 512 + kg;
            fp16x8 wh = *(const fp16x8*)&bt2_hi[eo];
            fp16x8 wl = *(const fp16x8*)&bt2_lo[eo];
            #pragma unroll
            for (int km = 0; km < 4; ++km)
                acc2[km][0] = __builtin_amdgcn_mfma_f32_16x16x32_f16(fah[km], wh, acc2[km][0], 0, 0, 0);
            #pragma unroll
            for (int km = 0; km < 4; ++km)
                acc2[km][0] = __builtin_amdgcn_mfma_f32_16x16x32_f16(fah[km], wl, acc2[km][0], 0, 0, 0);
            #pragma unroll
            for (int km = 0; km < 4; ++km)
                acc2[km][0] = __builtin_amdgcn_mfma_f32_16x16x32_f16(fal[km], wh, acc2[km][0], 0, 0, 0);
        }
        // ns = 1,2 (pure delta cols): 2-pass (w fp16 single, feat hi+lo)
        #pragma unroll
        for (int ns = 1; ns < 3; ++ns) {
            int eo = (ns * 16 + lr) * 512 + kg;
            fp16x8 wh = *(const fp16x8*)&bt2_hi[eo];
            #pragma unroll
            for (int km = 0; km < 4; ++km)
                acc2[km][ns] = __builtin_amdgcn_mfma_f32_16x16x32_f16(fah[km], wh, acc2[km][ns], 0, 0, 0);
            #pragma unroll
            for (int km = 0; km < 4; ++km)
                acc2[km][ns] = __builtin_amdgcn_mfma_f32_16x16x32_f16(fal[km], wh, acc2[km][ns], 0, 0, 0);
        }
    }

    // ---- deterministic staged cross-wave k-reduction (fixed FP order ->
    //      bitwise-identical output every launch) ----
    for (int w = 0; w < 4; ++w) {
        if (wave == w) {
            #pragma unroll
            for (int km = 0; km < 4; ++km)
                #pragma unroll
                for (int ns = 0; ns < 3; ++ns)
                    #pragma unroll
                    for (int r = 0; r < 4; ++r) {
                        int row = km * 16 + q * 4 + r;
                        int col = ns * 16 + lr;
                        float v = acc2[km][ns][r];
                        if (w == 0) zbuf[row * 48 + col] = v;
                        else        zbuf[row * 48 + col] += v;
                    }
        }
        __syncthreads();   // stage w complete before stage w+1 / epilogue
    }

    // ---- epilogue: sigmoid, threshold mask, nontemporal store ----
    for (int i = tid; i < 64 * 45; i += 256) {
        int m = i / 45;
        int o = i - m * 45;
        float z = zbuf[m * 48 + o];
        float v;
        if (o < 9) {
            v = 1.f / (1.f + expf(-(z + b_cls[o])));
        } else {
            int d = o - 9;
            int a = d >> 2;
            float s = 1.f / (1.f + expf(-(zbuf[m * 48 + a] + b_cls[a])));
            v = (s > 0.7f) ? (z + b_reg[d]) : 0.f;
        }
        int mh = m >> 5, mw = m & 31;
        __builtin_nontemporal_store(v, &out[(((b * 256 + h0 + mh) * 256) + w0 + mw) * 45 + o]);
    }
}

// ---------------------------------------------------------------------------
extern "C" void kernel_launch(void* const* d_in, const int* in_sizes, int n_in,
                              void* d_out, int out_size, void* d_ws, size_t ws_size,
                              hipStream_t stream)
{
    const float* x      = (const float*)d_in[0];
    const float* w_base = (const float*)d_in[1];
    const float* b_base = (const float*)d_in[2];
    const float* w_cls  = (const float*)d_in[3];
    const float* b_cls  = (const float*)d_in[4];
    const float* w_reg  = (const float*)d_in[5];
    const float* b_reg  = (const float*)d_in[6];
    float* out = (float*)d_out;

    _Float16* btI    = (_Float16*)d_ws;
    _Float16* bt2_hi = btI + BT_ELEMS;
    _Float16* bt2_lo = bt2_hi + BT2_ELEMS;

    rpn_prep<<<(BT_ELEMS + BT2_ELEMS + 255) / 256, 256, 0, stream>>>(
        w_base, w_cls, w_reg, btI, bt2_hi, bt2_lo);
    rpn_main<<<4096, 256, 0, stream>>>(
        x, b_base, b_cls, b_reg, btI, bt2_hi, bt2_lo, out);
}